// Round 2
// baseline (42.994 us; speedup 1.0000x reference)
//
#include <hip/hip_runtime.h>

// Problem constants (from reference): N=32768, H=6, W=8, C=14
constexpr int kN       = 32768;
constexpr int kCells   = 32768 * 6 * 8;      // 1,572,864 cells
constexpr int kThreads = 128;                // 2 waves / block, 1 cell / thread
constexpr int kBlocks  = kCells / kThreads;  // 12,288 (exact)
constexpr int kCellB   = 56;                 // 14 floats = 56 B per cell
constexpr int kWaveB   = 64 * kCellB;        // 3584 B per tensor per wave

constexpr float LAMBDA_COORD = 8.0f;
constexpr float LAMBDA_NOOBJ = 1.0f;
constexpr float LAMBDA_CLASS = 0.7f;
constexpr float EPS          = 1e-10f;

__device__ __forceinline__ float iou_box(float bx, float by, float bsw, float bsh,
                                         float gx, float gy, float gsw, float gsh) {
    float w1 = bsw * bsw, h1 = bsh * bsh;
    float w2 = gsw * gsw, h2 = gsh * gsh;
    float left  = fmaxf(bx - 0.5f * w1, gx - 0.5f * w2);
    float right = fminf(bx + 0.5f * w1, gx + 0.5f * w2);
    float top   = fmaxf(by - 0.5f * h1, gy - 0.5f * h2);
    float bot   = fminf(by + 0.5f * h1, gy + 0.5f * h2);
    float inter = fmaxf(right - left, 0.0f) * fmaxf(bot - top, 0.0f);
    float uni   = w1 * h1 + w2 * h2 - inter;
    return inter / (uni + EPS);
}

__device__ __forceinline__ float cell_loss(const float* o, const float* g) {
    float obj   = (g[4] > 0.0f) ? 1.0f : 0.0f;
    float noobj = 1.0f - obj;

    float iou0 = iou_box(o[0], o[1], o[2], o[3], g[0], g[1], g[2], g[3]);
    float iou1 = iou_box(o[5], o[6], o[7], o[8], g[0], g[1], g[2], g[3]);
    bool  s1   = iou1 > iou0;            // jnp.argmax picks first on ties -> idx=1 iff iou1>iou0
    float max_iou = fmaxf(iou0, iou1);

    float pr0 = s1 ? o[5] : o[0];
    float pr1 = s1 ? o[6] : o[1];
    float pr2 = s1 ? o[7] : o[2];
    float pr3 = s1 ? o[8] : o[3];
    float pr4 = s1 ? o[9] : o[4];
    float po4 = s1 ? o[4] : o[9];        // other pred conf

    float gr0 = s1 ? g[5] : g[0];
    float gr1 = s1 ? g[6] : g[1];
    float gr2 = s1 ? g[7] : g[2];
    float gr3 = s1 ? g[8] : g[3];
    float gn4 = s1 ? g[4] : g[9];        // other gt conf

    float d4 = o[4] - g[4], d9 = o[9] - g[9];
    float no_loss = noobj * (d4 * d4 + d9 * d9);

    float dcf  = pr4 - max_iou;
    float conf = dcf * dcf;

    float l0 = pr0 - gr0, l1 = pr1 - gr1, l2 = pr2 - gr2, l3 = pr3 - gr3;
    float loc = l0 * l0 + l1 * l1 + l2 * l2 + l3 * l3;

    float dnb = po4 - gn4;
    float nbc = dnb * dnb;

    float cls = 0.0f;
#pragma unroll
    for (int c = 10; c < 14; ++c) { float d = o[c] - g[c]; cls += d * d; }

    return LAMBDA_NOOBJ * no_loss +
           obj * (conf + LAMBDA_COORD * loc + LAMBDA_NOOBJ * nbc + LAMBDA_CLASS * cls);
}

// Async global->LDS, 16 B per lane. LDS dest = wave-uniform base + lane*16 (HW rule);
// global source is the per-lane address we pass.
__device__ __forceinline__ void gl_lds16(const void* g, void* l) {
    __builtin_amdgcn_global_load_lds(
        (const __attribute__((address_space(1))) unsigned int*)g,
        (__attribute__((address_space(3))) unsigned int*)l,
        16 /*bytes, literal*/, 0 /*offset*/, 0 /*aux*/);
}

__global__ __launch_bounds__(128) void yolo_partial(const float* __restrict__ outp,
                                                    const float* __restrict__ gtp,
                                                    float* __restrict__ partial) {
    // [wave][tensor o|g][3584 B], 16-B aligned. 14,336 B -> 11 blocks/CU.
    __shared__ float4 ldsv[2 * 2 * (kWaveB / 16)];
    __shared__ float  red[2];

    const int tid  = threadIdx.x;
    const int lane = tid & 63;
    const int wav  = tid >> 6;

    unsigned char* wBase = reinterpret_cast<unsigned char*>(ldsv) + wav * (2 * kWaveB);

    // This wave's 64 contiguous cells in global memory (3584 B per tensor, 16-B aligned).
    const size_t cell0 = (size_t)blockIdx.x * kThreads + (size_t)wav * 64;
    const unsigned char* gO = reinterpret_cast<const unsigned char*>(outp) + cell0 * kCellB;
    const unsigned char* gG = reinterpret_cast<const unsigned char*>(gtp)  + cell0 * kCellB;

    // Stage 3584 B per tensor: 3 full-wave 1024 B transfers + 1 half-wave 512 B.
    // Per-lane source addresses are contiguous (lane*16) -> perfectly coalesced.
#pragma unroll
    for (int k = 0; k < 3; ++k) {
        gl_lds16(gO + k * 1024 + lane * 16, wBase + k * 1024);
        gl_lds16(gG + k * 1024 + lane * 16, wBase + kWaveB + k * 1024);
    }
    if (lane < 32) {
        gl_lds16(gO + 3072 + lane * 16, wBase + 3072);
        gl_lds16(gG + 3072 + lane * 16, wBase + kWaveB + 3072);
    }

    // Wave-private: wait for OUR loads only; no block barrier, no lgkmcnt drain.
    __builtin_amdgcn_wave_barrier();
    asm volatile("s_waitcnt vmcnt(0)" ::: "memory");
    __builtin_amdgcn_wave_barrier();

    // Cell base = 56*lane: 8-B aligned for every lane -> ds_read_b64 x7 per tensor.
    const float2* po = reinterpret_cast<const float2*>(wBase + lane * kCellB);
    const float2* pg = reinterpret_cast<const float2*>(wBase + kWaveB + lane * kCellB);

    float o[14], g[14];
#pragma unroll
    for (int k = 0; k < 7; ++k) {
        float2 a = po[k];
        float2 b = pg[k];
        o[2 * k] = a.x; o[2 * k + 1] = a.y;
        g[2 * k] = b.x; g[2 * k + 1] = b.y;
    }

    float loss = cell_loss(o, g);

    // wave64 tree reduce
#pragma unroll
    for (int off = 32; off > 0; off >>= 1) loss += __shfl_down(loss, off, 64);
    if (lane == 0) red[wav] = loss;
    __syncthreads();
    if (tid == 0) partial[blockIdx.x] = red[0] + red[1];
}

__global__ __launch_bounds__(256) void yolo_final(const float* __restrict__ partial,
                                                  float* __restrict__ out) {
    __shared__ double red[4];
    double acc = 0.0;
    for (int i = threadIdx.x; i < kBlocks; i += 256) acc += (double)partial[i];
#pragma unroll
    for (int off = 32; off > 0; off >>= 1) acc += __shfl_down(acc, off, 64);
    int tid = threadIdx.x;
    if ((tid & 63) == 0) red[tid >> 6] = acc;
    __syncthreads();
    if (tid == 0) out[0] = (float)((red[0] + red[1] + red[2] + red[3]) * (1.0 / (double)kN));
}

extern "C" void kernel_launch(void* const* d_in, const int* in_sizes, int n_in,
                              void* d_out, int out_size, void* d_ws, size_t ws_size,
                              hipStream_t stream) {
    const float* outp = (const float*)d_in[0];   // output: (N,H,W,C) fp32
    const float* gtp  = (const float*)d_in[1];   // ground_truth: (N,H,W,C) fp32
    float* partial    = (float*)d_ws;            // 12,288 floats = 48 KB scratch
    float* out        = (float*)d_out;

    yolo_partial<<<kBlocks, kThreads, 0, stream>>>(outp, gtp, partial);
    yolo_final<<<1, 256, 0, stream>>>(partial, out);
}

// Round 3
// 32.454 us; speedup vs baseline: 1.3248x; 1.3248x over previous
//
#include <hip/hip_runtime.h>

// Problem constants (from reference): N=32768, H=6, W=8, C=14
constexpr int kN        = 32768;
constexpr int kCells    = 32768 * 6 * 8;        // 1,572,864 cells
constexpr int kThreads  = 256;                  // 4 waves / block
constexpr int kGrid     = 2048;                 // blocks
constexpr int kChunks   = kCells / kThreads;    // 6144 chunks of 256 cells
constexpr int kChunksPerBlk = kChunks / kGrid;  // 3 (exact)
constexpr int kCellB    = 56;                   // 14 floats per cell
constexpr int kWaveB    = 64 * kCellB;          // 3584 B per tensor per wave
constexpr int kWaveTot  = 2 * kWaveB;           // 7168 B per wave (o + g)

constexpr float LAMBDA_COORD = 8.0f;
constexpr float LAMBDA_NOOBJ = 1.0f;
constexpr float LAMBDA_CLASS = 0.7f;
constexpr float EPS          = 1e-10f;

__device__ __forceinline__ float iou_box(float bx, float by, float bsw, float bsh,
                                         float gx, float gy, float gsw, float gsh) {
    float w1 = bsw * bsw, h1 = bsh * bsh;
    float w2 = gsw * gsw, h2 = gsh * gsh;
    float left  = fmaxf(bx - 0.5f * w1, gx - 0.5f * w2);
    float right = fminf(bx + 0.5f * w1, gx + 0.5f * w2);
    float top   = fmaxf(by - 0.5f * h1, gy - 0.5f * h2);
    float bot   = fminf(by + 0.5f * h1, gy + 0.5f * h2);
    float inter = fmaxf(right - left, 0.0f) * fmaxf(bot - top, 0.0f);
    float uni   = w1 * h1 + w2 * h2 - inter;
    return inter / (uni + EPS);
}

__device__ __forceinline__ float cell_loss(const float* o, const float* g) {
    float obj   = (g[4] > 0.0f) ? 1.0f : 0.0f;
    float noobj = 1.0f - obj;

    float iou0 = iou_box(o[0], o[1], o[2], o[3], g[0], g[1], g[2], g[3]);
    float iou1 = iou_box(o[5], o[6], o[7], o[8], g[0], g[1], g[2], g[3]);
    bool  s1   = iou1 > iou0;            // jnp.argmax picks first on ties -> idx=1 iff iou1>iou0
    float max_iou = fmaxf(iou0, iou1);

    float pr0 = s1 ? o[5] : o[0];
    float pr1 = s1 ? o[6] : o[1];
    float pr2 = s1 ? o[7] : o[2];
    float pr3 = s1 ? o[8] : o[3];
    float pr4 = s1 ? o[9] : o[4];
    float po4 = s1 ? o[4] : o[9];        // other pred conf

    float gr0 = s1 ? g[5] : g[0];
    float gr1 = s1 ? g[6] : g[1];
    float gr2 = s1 ? g[7] : g[2];
    float gr3 = s1 ? g[8] : g[3];
    float gn4 = s1 ? g[4] : g[9];        // other gt conf

    float d4 = o[4] - g[4], d9 = o[9] - g[9];
    float no_loss = noobj * (d4 * d4 + d9 * d9);

    float dcf  = pr4 - max_iou;
    float conf = dcf * dcf;

    float l0 = pr0 - gr0, l1 = pr1 - gr1, l2 = pr2 - gr2, l3 = pr3 - gr3;
    float loc = l0 * l0 + l1 * l1 + l2 * l2 + l3 * l3;

    float dnb = po4 - gn4;
    float nbc = dnb * dnb;

    float cls = 0.0f;
#pragma unroll
    for (int c = 10; c < 14; ++c) { float d = o[c] - g[c]; cls += d * d; }

    return LAMBDA_NOOBJ * no_loss +
           obj * (conf + LAMBDA_COORD * loc + LAMBDA_NOOBJ * nbc + LAMBDA_CLASS * cls);
}

// Async global->LDS, 16 B per lane. LDS dest = wave-uniform base + lane*16 (HW rule);
// GLOBAL source address is per-lane (may even point at different tensors per lane).
__device__ __forceinline__ void gl_lds16(const void* g, void* l) {
    __builtin_amdgcn_global_load_lds(
        (const __attribute__((address_space(1))) unsigned int*)g,
        (__attribute__((address_space(3))) unsigned int*)l,
        16 /*bytes, literal*/, 0 /*offset*/, 0 /*aux*/);
}

__global__ __launch_bounds__(256) void yolo_partial(const float* __restrict__ outp,
                                                    const float* __restrict__ gtp,
                                                    float* __restrict__ partial) {
    // Per-wave private staging: [wave][o:3584 | g:3584]. 28,672 B -> 5 blocks/CU.
    __shared__ __attribute__((aligned(16))) unsigned char lds[4 * kWaveTot];
    __shared__ float red[4];

    const int tid  = threadIdx.x;
    const int lane = tid & 63;
    const int wav  = tid >> 6;
    unsigned char* wBase = lds + wav * kWaveTot;

    float loss = 0.0f;

    // 3 contiguous chunks per block; each wave owns 64 contiguous cells per chunk.
    for (int j = 0; j < kChunksPerBlk; ++j) {
        const size_t chunk = (size_t)blockIdx.x * kChunksPerBlk + j;
        const size_t cell0 = chunk * kThreads + (size_t)wav * 64;
        const unsigned char* gO = reinterpret_cast<const unsigned char*>(outp) + cell0 * kCellB;
        const unsigned char* gG = reinterpret_cast<const unsigned char*>(gtp)  + cell0 * kCellB;

        if (j) {
            // Ensure prior chunk's ds_reads drained before overwriting LDS.
            asm volatile("s_waitcnt lgkmcnt(0)" ::: "memory");
            __builtin_amdgcn_sched_barrier(0);
        }

        // 7 x 1024 B transfers cover both tensors; transfer 3 splits lanes across o/g.
#pragma unroll
        for (int t = 0; t < 7; ++t) {
            const int p = t * 1024 + lane * 16;
            const unsigned char* src = (p < kWaveB) ? (gO + p) : (gG + (p - kWaveB));
            gl_lds16(src, wBase + t * 1024);
        }

        // Wave-private wait: only OUR loads; no block barrier.
        __builtin_amdgcn_wave_barrier();
        asm volatile("s_waitcnt vmcnt(0)" ::: "memory");
        __builtin_amdgcn_wave_barrier();

        // Cell base = 56*lane: 8-B aligned -> ds_read_b64 x7 per tensor.
        const float2* po = reinterpret_cast<const float2*>(wBase + lane * kCellB);
        const float2* pg = reinterpret_cast<const float2*>(wBase + kWaveB + lane * kCellB);

        float o[14], g[14];
#pragma unroll
        for (int k = 0; k < 7; ++k) {
            float2 a = po[k];
            float2 b = pg[k];
            o[2 * k] = a.x; o[2 * k + 1] = a.y;
            g[2 * k] = b.x; g[2 * k + 1] = b.y;
        }

        loss += cell_loss(o, g);
    }

    // wave64 tree reduce, then one cross-wave combine per block lifetime.
#pragma unroll
    for (int off = 32; off > 0; off >>= 1) loss += __shfl_down(loss, off, 64);
    if (lane == 0) red[wav] = loss;
    __syncthreads();
    if (tid == 0) partial[blockIdx.x] = red[0] + red[1] + red[2] + red[3];
}

__global__ __launch_bounds__(256) void yolo_final(const float* __restrict__ partial,
                                                  float* __restrict__ out) {
    __shared__ double red[4];
    // 2048 partials = 512 float4; 256 threads read 2 float4 each.
    const float4* p4 = reinterpret_cast<const float4*>(partial);
    double acc = 0.0;
#pragma unroll
    for (int k = 0; k < 2; ++k) {
        float4 v = p4[threadIdx.x + k * 256];
        acc += (double)v.x + (double)v.y + (double)v.z + (double)v.w;
    }
#pragma unroll
    for (int off = 32; off > 0; off >>= 1) acc += __shfl_down(acc, off, 64);
    int tid = threadIdx.x;
    if ((tid & 63) == 0) red[tid >> 6] = acc;
    __syncthreads();
    if (tid == 0) out[0] = (float)((red[0] + red[1] + red[2] + red[3]) * (1.0 / (double)kN));
}

extern "C" void kernel_launch(void* const* d_in, const int* in_sizes, int n_in,
                              void* d_out, int out_size, void* d_ws, size_t ws_size,
                              hipStream_t stream) {
    const float* outp = (const float*)d_in[0];   // output: (N,H,W,C) fp32
    const float* gtp  = (const float*)d_in[1];   // ground_truth: (N,H,W,C) fp32
    float* partial    = (float*)d_ws;            // 2048 floats = 8 KB scratch
    float* out        = (float*)d_out;

    yolo_partial<<<kGrid, kThreads, 0, stream>>>(outp, gtp, partial);
    yolo_final<<<1, 256, 0, stream>>>(partial, out);
}